// Round 1
// baseline (2599.471 us; speedup 1.0000x reference)
//
#include <hip/hip_runtime.h>

#define NEG_INF_BITS 0xFF800000u

__device__ __forceinline__ void atomicMaxFloat(float* addr, float val) {
    // Signed-max for non-negative, unsigned-min for negative.
    // Correct for mixed signs given init = -inf (0xFF800000).
    if (val >= 0.0f) {
        atomicMax((int*)addr, __float_as_int(val));
    } else {
        atomicMin((unsigned int*)addr, (unsigned int)__float_as_uint(val));
    }
}

// ---------------------------------------------------------------------------
// 1) init: out <- -inf (mode==1) or 0; counts <- 0
// ---------------------------------------------------------------------------
__global__ void seg_init_kernel(unsigned int* __restrict__ out, int out_n,
                                float* __restrict__ counts, int nseg,
                                const int* __restrict__ mode_p) {
    const int mode = mode_p[0];
    const unsigned int initv = (mode == 1) ? NEG_INF_BITS : 0u;
    const int stride = gridDim.x * blockDim.x;
    int i = blockIdx.x * blockDim.x + threadIdx.x;
    // vectorized: out_n is a multiple of 4
    uint4* out4 = (uint4*)out;
    const int n4 = out_n >> 2;
    uint4 v4 = make_uint4(initv, initv, initv, initv);
    for (int j = i; j < n4; j += stride) out4[j] = v4;
    for (int j = i; j < nseg; j += stride) counts[j] = 0.0f;
}

// ---------------------------------------------------------------------------
// 2) scatter: 32 threads per row; float4 per thread; atomic max/add into out
// ---------------------------------------------------------------------------
__global__ void seg_scatter_kernel(const float4* __restrict__ feat4,
                                   const int* __restrict__ inv,
                                   float* __restrict__ out,
                                   float* __restrict__ counts,
                                   int nrows,
                                   const int* __restrict__ mode_p) {
    const int mode = mode_p[0];
    const int t = blockIdx.x * blockDim.x + threadIdx.x;
    const int row = t >> 5;      // 32 threads per row (128 cols / 4)
    const int q   = t & 31;      // float4 slot within the row
    if (row >= nrows) return;

    const int seg = inv[row];
    const float4 v = feat4[(size_t)row * 32 + q];
    float* dst = out + (size_t)seg * 128 + q * 4;

    if (mode == 1) {
        atomicMaxFloat(dst + 0, v.x);
        atomicMaxFloat(dst + 1, v.y);
        atomicMaxFloat(dst + 2, v.z);
        atomicMaxFloat(dst + 3, v.w);
        if (q == 0) atomicAdd(&counts[seg], 1.0f);
    } else {
        atomicAdd(dst + 0, v.x);
        atomicAdd(dst + 1, v.y);
        atomicAdd(dst + 2, v.z);
        atomicAdd(dst + 3, v.w);
        if (mode == 2 && q == 0) atomicAdd(&counts[seg], 1.0f);
    }
}

// ---------------------------------------------------------------------------
// 3) fixup: empty segments -> 0 (mode 1); divide by counts (mode 2)
// ---------------------------------------------------------------------------
__global__ void seg_fixup_kernel(float* __restrict__ out, int out_n,
                                 const float* __restrict__ counts,
                                 const int* __restrict__ mode_p) {
    const int mode = mode_p[0];
    if (mode == 3) return;
    const int i = blockIdx.x * blockDim.x + threadIdx.x;
    if (i >= out_n) return;
    const int seg = i >> 7;   // 128 cols
    const float c = counts[seg];
    if (mode == 1) {
        if (c == 0.0f) out[i] = 0.0f;
    } else {  // mode 2: mean
        out[i] = out[i] / fmaxf(c, 1.0f);
    }
}

extern "C" void kernel_launch(void* const* d_in, const int* in_sizes, int n_in,
                              void* d_out, int out_size, void* d_ws, size_t ws_size,
                              hipStream_t stream) {
    const float* feat   = (const float*)d_in[0];
    const int*   inv    = (const int*)d_in[1];
    const int*   mode_p = (const int*)d_in[2];
    float* out = (float*)d_out;

    const int nrows = in_sizes[1];           // 1,000,000
    const int nseg  = out_size / 128;        // 65,536
    float* counts = (float*)d_ws;            // 256 KB of ws

    // 1) init
    {
        dim3 block(256);
        dim3 grid(2048);
        seg_init_kernel<<<grid, block, 0, stream>>>((unsigned int*)out, out_size,
                                                    counts, nseg, mode_p);
    }

    // 2) scatter (32 threads per row)
    {
        const long long total = (long long)nrows * 32;
        dim3 block(256);
        dim3 grid((unsigned int)((total + 255) / 256));
        seg_scatter_kernel<<<grid, block, 0, stream>>>((const float4*)feat, inv,
                                                       out, counts, nrows, mode_p);
    }

    // 3) fixup
    {
        dim3 block(256);
        dim3 grid((out_size + 255) / 256);
        seg_fixup_kernel<<<grid, block, 0, stream>>>(out, out_size, counts, mode_p);
    }
}

// Round 2
// 406.602 us; speedup vs baseline: 6.3932x; 6.3932x over previous
//
#include <hip/hip_runtime.h>
#include <math.h>

#define NEG_INF_BITS 0xFF800000u

// ===========================================================================
// CSR path: histogram -> scan -> scatter indices -> gather-reduce
// ===========================================================================

// A) histogram: counts[seg]++ for each row
__global__ void hist_kernel(const int* __restrict__ inv,
                            int* __restrict__ counts, int n) {
    const int stride = gridDim.x * blockDim.x;
    for (int i = blockIdx.x * blockDim.x + threadIdx.x; i < n; i += stride) {
        atomicAdd(&counts[inv[i]], 1);
    }
}

// B) exclusive scan of counts (nseg elements) -> offsets[0..nseg] and cursor copy.
//    Single block, 1024 threads, each owns a contiguous chunk.
__global__ __launch_bounds__(1024)
void scan_kernel(const int* __restrict__ counts,
                 int* __restrict__ offsets,
                 int* __restrict__ cursor, int nseg) {
    __shared__ int lds[1024];
    const int t = threadIdx.x;
    const int CH = (nseg + 1023) >> 10;   // chunk per thread
    const int base = t * CH;

    int sum = 0;
    for (int i = 0; i < CH; i++) {
        int idx = base + i;
        if (idx < nseg) sum += counts[idx];
    }
    lds[t] = sum;
    __syncthreads();

    // Hillis-Steele inclusive scan over 1024 partials
    for (int off = 1; off < 1024; off <<= 1) {
        int v = lds[t];
        int add = (t >= off) ? lds[t - off] : 0;
        __syncthreads();
        lds[t] = v + add;
        __syncthreads();
    }
    int run = (t == 0) ? 0 : lds[t - 1];
    if (t == 1023) offsets[nseg] = lds[1023];

    for (int i = 0; i < CH; i++) {
        int idx = base + i;
        if (idx < nseg) {
            offsets[idx] = run;
            cursor[idx] = run;
            run += counts[idx];
        }
    }
}

// C) scatter row indices into CSR order
__global__ void scatteridx_kernel(const int* __restrict__ inv,
                                  int* __restrict__ cursor,
                                  int* __restrict__ rowidx, int n) {
    const int stride = gridDim.x * blockDim.x;
    for (int i = blockIdx.x * blockDim.x + threadIdx.x; i < n; i += stride) {
        int s = inv[i];
        int p = atomicAdd(&cursor[s], 1);
        rowidx[p] = i;
    }
}

// D) gather-reduce: 32 lanes per segment, float4 per lane (128 cols)
__global__ void seg_reduce_kernel(const float4* __restrict__ feat4,
                                  const int* __restrict__ rowidx,
                                  const int* __restrict__ offsets,
                                  float4* __restrict__ out4,
                                  int nseg,
                                  const int* __restrict__ mode_p) {
    const int mode = mode_p[0];
    const int t = blockIdx.x * blockDim.x + threadIdx.x;
    const int g = t >> 5;          // segment
    const int q = t & 31;          // float4 column slot
    if (g >= nseg) return;

    const int start = offsets[g];
    const int end   = offsets[g + 1];

    float4 acc;
    if (mode == 1) {
        acc = make_float4(-INFINITY, -INFINITY, -INFINITY, -INFINITY);
        for (int r = start; r < end; r++) {
            const int row = rowidx[r];
            const float4 v = feat4[(size_t)row * 32 + q];
            acc.x = fmaxf(acc.x, v.x);
            acc.y = fmaxf(acc.y, v.y);
            acc.z = fmaxf(acc.z, v.z);
            acc.w = fmaxf(acc.w, v.w);
        }
        if (end == start) acc = make_float4(0.f, 0.f, 0.f, 0.f);  // empty -> 0
    } else {
        acc = make_float4(0.f, 0.f, 0.f, 0.f);
        for (int r = start; r < end; r++) {
            const int row = rowidx[r];
            const float4 v = feat4[(size_t)row * 32 + q];
            acc.x += v.x; acc.y += v.y; acc.z += v.z; acc.w += v.w;
        }
        if (mode == 2) {
            const float c = fmaxf((float)(end - start), 1.0f);
            acc.x /= c; acc.y /= c; acc.z /= c; acc.w /= c;
        }
    }
    out4[(size_t)g * 32 + q] = acc;
}

// ===========================================================================
// Fallback (atomic path) — only used if ws_size is too small for CSR
// ===========================================================================
__device__ __forceinline__ void atomicMaxFloat(float* addr, float val) {
    if (val >= 0.0f) atomicMax((int*)addr, __float_as_int(val));
    else             atomicMin((unsigned int*)addr, (unsigned int)__float_as_uint(val));
}

__global__ void fb_init_kernel(unsigned int* __restrict__ out, int out_n,
                               float* __restrict__ counts, int nseg,
                               const int* __restrict__ mode_p) {
    const int mode = mode_p[0];
    const unsigned int initv = (mode == 1) ? NEG_INF_BITS : 0u;
    const int stride = gridDim.x * blockDim.x;
    int i = blockIdx.x * blockDim.x + threadIdx.x;
    uint4* out4 = (uint4*)out;
    const int n4 = out_n >> 2;
    uint4 v4 = make_uint4(initv, initv, initv, initv);
    for (int j = i; j < n4; j += stride) out4[j] = v4;
    for (int j = i; j < nseg; j += stride) counts[j] = 0.0f;
}

__global__ void fb_scatter_kernel(const float4* __restrict__ feat4,
                                  const int* __restrict__ inv,
                                  float* __restrict__ out,
                                  float* __restrict__ counts,
                                  int nrows, const int* __restrict__ mode_p) {
    const int mode = mode_p[0];
    const int t = blockIdx.x * blockDim.x + threadIdx.x;
    const int row = t >> 5;
    const int q   = t & 31;
    if (row >= nrows) return;
    const int seg = inv[row];
    const float4 v = feat4[(size_t)row * 32 + q];
    float* dst = out + (size_t)seg * 128 + q * 4;
    if (mode == 1) {
        atomicMaxFloat(dst + 0, v.x); atomicMaxFloat(dst + 1, v.y);
        atomicMaxFloat(dst + 2, v.z); atomicMaxFloat(dst + 3, v.w);
        if (q == 0) atomicAdd(&counts[seg], 1.0f);
    } else {
        atomicAdd(dst + 0, v.x); atomicAdd(dst + 1, v.y);
        atomicAdd(dst + 2, v.z); atomicAdd(dst + 3, v.w);
        if (mode == 2 && q == 0) atomicAdd(&counts[seg], 1.0f);
    }
}

__global__ void fb_fixup_kernel(float* __restrict__ out, int out_n,
                                const float* __restrict__ counts,
                                const int* __restrict__ mode_p) {
    const int mode = mode_p[0];
    if (mode == 3) return;
    const int i = blockIdx.x * blockDim.x + threadIdx.x;
    if (i >= out_n) return;
    const int seg = i >> 7;
    const float c = counts[seg];
    if (mode == 1) { if (c == 0.0f) out[i] = 0.0f; }
    else           { out[i] = out[i] / fmaxf(c, 1.0f); }
}

// ===========================================================================
extern "C" void kernel_launch(void* const* d_in, const int* in_sizes, int n_in,
                              void* d_out, int out_size, void* d_ws, size_t ws_size,
                              hipStream_t stream) {
    const float* feat   = (const float*)d_in[0];
    const int*   inv    = (const int*)d_in[1];
    const int*   mode_p = (const int*)d_in[2];
    float* out = (float*)d_out;

    const int nrows = in_sizes[1];         // 1,000,000
    const int nseg  = out_size / 128;      // 65,536

    // ws layout: counts[nseg] | offsets[nseg+1] | cursor[nseg] | rowidx[nrows]
    const size_t need = (size_t)(nseg + (nseg + 1) + nseg + nrows) * sizeof(int);

    if (ws_size >= need) {
        int* counts  = (int*)d_ws;
        int* offsets = counts + nseg;
        int* cursor  = offsets + (nseg + 1);
        int* rowidx  = cursor + nseg;

        // zero counts
        hipMemsetAsync(counts, 0, (size_t)nseg * sizeof(int), stream);

        // A) histogram
        {
            dim3 block(256), grid(2048);
            hist_kernel<<<grid, block, 0, stream>>>(inv, counts, nrows);
        }
        // B) scan
        scan_kernel<<<1, 1024, 0, stream>>>(counts, offsets, cursor, nseg);
        // C) scatter row indices
        {
            dim3 block(256), grid(2048);
            scatteridx_kernel<<<grid, block, 0, stream>>>(inv, cursor, rowidx, nrows);
        }
        // D) gather-reduce
        {
            const long long total = (long long)nseg * 32;
            dim3 block(256), grid((unsigned int)((total + 255) / 256));
            seg_reduce_kernel<<<grid, block, 0, stream>>>((const float4*)feat, rowidx,
                                                          offsets, (float4*)out,
                                                          nseg, mode_p);
        }
    } else {
        // fallback: atomic path
        float* counts = (float*)d_ws;
        {
            dim3 block(256), grid(2048);
            fb_init_kernel<<<grid, block, 0, stream>>>((unsigned int*)out, out_size,
                                                       counts, nseg, mode_p);
        }
        {
            const long long total = (long long)nrows * 32;
            dim3 block(256), grid((unsigned int)((total + 255) / 256));
            fb_scatter_kernel<<<grid, block, 0, stream>>>((const float4*)feat, inv,
                                                          out, counts, nrows, mode_p);
        }
        {
            dim3 block(256), grid((out_size + 255) / 256);
            fb_fixup_kernel<<<grid, block, 0, stream>>>(out, out_size, counts, mode_p);
        }
    }
}

// Round 3
// 386.200 us; speedup vs baseline: 6.7309x; 1.0528x over previous
//
#include <hip/hip_runtime.h>
#include <math.h>

#define NEG_INF_BITS 0xFF800000u

// ===========================================================================
// CSR path: zero -> histogram -> scan -> scatter indices -> gather-reduce
// ===========================================================================

// A0) zero counts (replaces hipMemsetAsync: graph memset node measured 300us!)
__global__ void zero_counts_kernel(int* __restrict__ counts, int nseg) {
    const int i = blockIdx.x * blockDim.x + threadIdx.x;
    if (i < nseg) counts[i] = 0;
}

// A) histogram: counts[seg]++ for each row
__global__ void hist_kernel(const int* __restrict__ inv,
                            int* __restrict__ counts, int n) {
    const int stride = gridDim.x * blockDim.x;
    for (int i = blockIdx.x * blockDim.x + threadIdx.x; i < n; i += stride) {
        atomicAdd(&counts[inv[i]], 1);
    }
}

// B) exclusive scan of counts (nseg elements) -> offsets[0..nseg] and cursor copy.
__global__ __launch_bounds__(1024)
void scan_kernel(const int* __restrict__ counts,
                 int* __restrict__ offsets,
                 int* __restrict__ cursor, int nseg) {
    __shared__ int lds[1024];
    const int t = threadIdx.x;
    const int CH = (nseg + 1023) >> 10;   // chunk per thread
    const int base = t * CH;

    int sum = 0;
    for (int i = 0; i < CH; i++) {
        int idx = base + i;
        if (idx < nseg) sum += counts[idx];
    }
    lds[t] = sum;
    __syncthreads();

    for (int off = 1; off < 1024; off <<= 1) {
        int v = lds[t];
        int add = (t >= off) ? lds[t - off] : 0;
        __syncthreads();
        lds[t] = v + add;
        __syncthreads();
    }
    int run = (t == 0) ? 0 : lds[t - 1];
    if (t == 1023) offsets[nseg] = lds[1023];

    for (int i = 0; i < CH; i++) {
        int idx = base + i;
        if (idx < nseg) {
            offsets[idx] = run;
            cursor[idx] = run;
            run += counts[idx];
        }
    }
}

// C) scatter row indices into CSR order
__global__ void scatteridx_kernel(const int* __restrict__ inv,
                                  int* __restrict__ cursor,
                                  int* __restrict__ rowidx, int n) {
    const int stride = gridDim.x * blockDim.x;
    for (int i = blockIdx.x * blockDim.x + threadIdx.x; i < n; i += stride) {
        int s = inv[i];
        int p = atomicAdd(&cursor[s], 1);
        rowidx[p] = i;
    }
}

// D) gather-reduce: 32 lanes per segment, float4 per lane (128 cols)
__global__ void seg_reduce_kernel(const float4* __restrict__ feat4,
                                  const int* __restrict__ rowidx,
                                  const int* __restrict__ offsets,
                                  float4* __restrict__ out4,
                                  int nseg,
                                  const int* __restrict__ mode_p) {
    const int mode = mode_p[0];
    const int t = blockIdx.x * blockDim.x + threadIdx.x;
    const int g = t >> 5;          // segment
    const int q = t & 31;          // float4 column slot
    if (g >= nseg) return;

    const int start = offsets[g];
    const int end   = offsets[g + 1];

    float4 acc;
    if (mode == 1) {
        acc = make_float4(-INFINITY, -INFINITY, -INFINITY, -INFINITY);
        int r = start;
        for (; r + 2 <= end; r += 2) {
            const int row0 = rowidx[r];
            const int row1 = rowidx[r + 1];
            const float4 v0 = feat4[(size_t)row0 * 32 + q];
            const float4 v1 = feat4[(size_t)row1 * 32 + q];
            acc.x = fmaxf(acc.x, fmaxf(v0.x, v1.x));
            acc.y = fmaxf(acc.y, fmaxf(v0.y, v1.y));
            acc.z = fmaxf(acc.z, fmaxf(v0.z, v1.z));
            acc.w = fmaxf(acc.w, fmaxf(v0.w, v1.w));
        }
        if (r < end) {
            const int row = rowidx[r];
            const float4 v = feat4[(size_t)row * 32 + q];
            acc.x = fmaxf(acc.x, v.x); acc.y = fmaxf(acc.y, v.y);
            acc.z = fmaxf(acc.z, v.z); acc.w = fmaxf(acc.w, v.w);
        }
        if (end == start) acc = make_float4(0.f, 0.f, 0.f, 0.f);  // empty -> 0
    } else {
        acc = make_float4(0.f, 0.f, 0.f, 0.f);
        int r = start;
        for (; r + 2 <= end; r += 2) {
            const int row0 = rowidx[r];
            const int row1 = rowidx[r + 1];
            const float4 v0 = feat4[(size_t)row0 * 32 + q];
            const float4 v1 = feat4[(size_t)row1 * 32 + q];
            acc.x += v0.x + v1.x; acc.y += v0.y + v1.y;
            acc.z += v0.z + v1.z; acc.w += v0.w + v1.w;
        }
        if (r < end) {
            const int row = rowidx[r];
            const float4 v = feat4[(size_t)row * 32 + q];
            acc.x += v.x; acc.y += v.y; acc.z += v.z; acc.w += v.w;
        }
        if (mode == 2) {
            const float c = fmaxf((float)(end - start), 1.0f);
            acc.x /= c; acc.y /= c; acc.z /= c; acc.w /= c;
        }
    }
    out4[(size_t)g * 32 + q] = acc;
}

// ===========================================================================
// Fallback (atomic path) — only used if ws_size is too small for CSR
// ===========================================================================
__device__ __forceinline__ void atomicMaxFloat(float* addr, float val) {
    if (val >= 0.0f) atomicMax((int*)addr, __float_as_int(val));
    else             atomicMin((unsigned int*)addr, (unsigned int)__float_as_uint(val));
}

__global__ void fb_init_kernel(unsigned int* __restrict__ out, int out_n,
                               float* __restrict__ counts, int nseg,
                               const int* __restrict__ mode_p) {
    const int mode = mode_p[0];
    const unsigned int initv = (mode == 1) ? NEG_INF_BITS : 0u;
    const int stride = gridDim.x * blockDim.x;
    int i = blockIdx.x * blockDim.x + threadIdx.x;
    uint4* out4 = (uint4*)out;
    const int n4 = out_n >> 2;
    uint4 v4 = make_uint4(initv, initv, initv, initv);
    for (int j = i; j < n4; j += stride) out4[j] = v4;
    for (int j = i; j < nseg; j += stride) counts[j] = 0.0f;
}

__global__ void fb_scatter_kernel(const float4* __restrict__ feat4,
                                  const int* __restrict__ inv,
                                  float* __restrict__ out,
                                  float* __restrict__ counts,
                                  int nrows, const int* __restrict__ mode_p) {
    const int mode = mode_p[0];
    const int t = blockIdx.x * blockDim.x + threadIdx.x;
    const int row = t >> 5;
    const int q   = t & 31;
    if (row >= nrows) return;
    const int seg = inv[row];
    const float4 v = feat4[(size_t)row * 32 + q];
    float* dst = out + (size_t)seg * 128 + q * 4;
    if (mode == 1) {
        atomicMaxFloat(dst + 0, v.x); atomicMaxFloat(dst + 1, v.y);
        atomicMaxFloat(dst + 2, v.z); atomicMaxFloat(dst + 3, v.w);
        if (q == 0) atomicAdd(&counts[seg], 1.0f);
    } else {
        atomicAdd(dst + 0, v.x); atomicAdd(dst + 1, v.y);
        atomicAdd(dst + 2, v.z); atomicAdd(dst + 3, v.w);
        if (mode == 2 && q == 0) atomicAdd(&counts[seg], 1.0f);
    }
}

__global__ void fb_fixup_kernel(float* __restrict__ out, int out_n,
                                const float* __restrict__ counts,
                                const int* __restrict__ mode_p) {
    const int mode = mode_p[0];
    if (mode == 3) return;
    const int i = blockIdx.x * blockDim.x + threadIdx.x;
    if (i >= out_n) return;
    const int seg = i >> 7;
    const float c = counts[seg];
    if (mode == 1) { if (c == 0.0f) out[i] = 0.0f; }
    else           { out[i] = out[i] / fmaxf(c, 1.0f); }
}

// ===========================================================================
extern "C" void kernel_launch(void* const* d_in, const int* in_sizes, int n_in,
                              void* d_out, int out_size, void* d_ws, size_t ws_size,
                              hipStream_t stream) {
    const float* feat   = (const float*)d_in[0];
    const int*   inv    = (const int*)d_in[1];
    const int*   mode_p = (const int*)d_in[2];
    float* out = (float*)d_out;

    const int nrows = in_sizes[1];         // 1,000,000
    const int nseg  = out_size / 128;      // 65,536

    // ws layout: counts[nseg] | offsets[nseg+1] | cursor[nseg] | rowidx[nrows]
    const size_t need = (size_t)(nseg + (nseg + 1) + nseg + nrows) * sizeof(int);

    if (ws_size >= need) {
        int* counts  = (int*)d_ws;
        int* offsets = counts + nseg;
        int* cursor  = offsets + (nseg + 1);
        int* rowidx  = cursor + nseg;

        // A0) zero counts with our own kernel (graph memset node was ~300us!)
        {
            dim3 block(256), grid((nseg + 255) / 256);
            zero_counts_kernel<<<grid, block, 0, stream>>>(counts, nseg);
        }
        // A) histogram
        {
            dim3 block(256), grid(2048);
            hist_kernel<<<grid, block, 0, stream>>>(inv, counts, nrows);
        }
        // B) scan
        scan_kernel<<<1, 1024, 0, stream>>>(counts, offsets, cursor, nseg);
        // C) scatter row indices
        {
            dim3 block(256), grid(2048);
            scatteridx_kernel<<<grid, block, 0, stream>>>(inv, cursor, rowidx, nrows);
        }
        // D) gather-reduce
        {
            const long long total = (long long)nseg * 32;
            dim3 block(256), grid((unsigned int)((total + 255) / 256));
            seg_reduce_kernel<<<grid, block, 0, stream>>>((const float4*)feat, rowidx,
                                                          offsets, (float4*)out,
                                                          nseg, mode_p);
        }
    } else {
        // fallback: atomic path
        float* counts = (float*)d_ws;
        {
            dim3 block(256), grid(2048);
            fb_init_kernel<<<grid, block, 0, stream>>>((unsigned int*)out, out_size,
                                                       counts, nseg, mode_p);
        }
        {
            const long long total = (long long)nrows * 32;
            dim3 block(256), grid((unsigned int)((total + 255) / 256));
            fb_scatter_kernel<<<grid, block, 0, stream>>>((const float4*)feat, inv,
                                                          out, counts, nrows, mode_p);
        }
        {
            dim3 block(256), grid((out_size + 255) / 256);
            fb_fixup_kernel<<<grid, block, 0, stream>>>(out, out_size, counts, mode_p);
        }
    }
}

// Round 4
// 231.138 us; speedup vs baseline: 11.2464x; 1.6709x over previous
//
#include <hip/hip_runtime.h>
#include <math.h>

#define NEG_INF_BITS 0xFF800000u
#define SCAN_B 1024   // threads per scan block (= tile size)

// ===========================================================================
// CSR path: zero -> histogram -> 3-pass scan -> scatter indices -> gather-reduce
// ===========================================================================

__global__ void zero_counts_kernel(int* __restrict__ counts, int nseg) {
    const int i = blockIdx.x * blockDim.x + threadIdx.x;
    if (i < nseg) counts[i] = 0;
}

// A) histogram: counts[seg]++ for each row (int4-vectorized loads)
__global__ void hist_kernel(const int* __restrict__ inv,
                            int* __restrict__ counts, int n) {
    const int stride = gridDim.x * blockDim.x;
    const int n4 = n >> 2;
    const int4* inv4 = (const int4*)inv;
    for (int i = blockIdx.x * blockDim.x + threadIdx.x; i < n4; i += stride) {
        int4 s = inv4[i];
        atomicAdd(&counts[s.x], 1);
        atomicAdd(&counts[s.y], 1);
        atomicAdd(&counts[s.z], 1);
        atomicAdd(&counts[s.w], 1);
    }
    // tail
    if (blockIdx.x == 0 && threadIdx.x < (n & 3)) {
        atomicAdd(&counts[inv[(n4 << 2) + threadIdx.x]], 1);
    }
}

// B1) per-block reduce of counts tiles -> bsum[block]
__global__ __launch_bounds__(SCAN_B)
void scan_reduce_kernel(const int* __restrict__ counts,
                        int* __restrict__ bsum, int nseg) {
    __shared__ int lds[SCAN_B / 64];
    const int t = threadIdx.x;
    const int idx = blockIdx.x * SCAN_B + t;
    int v = (idx < nseg) ? counts[idx] : 0;
    // wave reduce (64 lanes)
    for (int off = 32; off > 0; off >>= 1) v += __shfl_down(v, off, 64);
    if ((t & 63) == 0) lds[t >> 6] = v;
    __syncthreads();
    if (t < SCAN_B / 64) {
        int s = lds[t];
        for (int off = SCAN_B / 128; off > 0; off >>= 1) s += __shfl_down(s, off, 64);
        if (t == 0) bsum[blockIdx.x] = s;
    }
}

// B2) single small block: exclusive scan of bsum[nblk]; writes offsets[nseg]=total
__global__ __launch_bounds__(SCAN_B)
void scan_top_kernel(int* __restrict__ bsum, int* __restrict__ offsets,
                     int nblk, int nseg) {
    __shared__ int lds[SCAN_B];
    const int t = threadIdx.x;
    int v = (t < nblk) ? bsum[t] : 0;
    lds[t] = v;
    __syncthreads();
    for (int off = 1; off < SCAN_B; off <<= 1) {
        int x = lds[t];
        int add = (t >= off) ? lds[t - off] : 0;
        __syncthreads();
        lds[t] = x + add;
        __syncthreads();
    }
    if (t < nblk) bsum[t] = lds[t] - v;              // exclusive
    if (t == nblk - 1) offsets[nseg] = lds[t];       // total
}

// B3) per-block scan of counts tile + bsum prefix -> offsets, cursor
__global__ __launch_bounds__(SCAN_B)
void scan_down_kernel(const int* __restrict__ counts,
                      const int* __restrict__ bsum,
                      int* __restrict__ offsets,
                      int* __restrict__ cursor, int nseg) {
    __shared__ int lds[SCAN_B];
    const int t = threadIdx.x;
    const int idx = blockIdx.x * SCAN_B + t;
    int c = (idx < nseg) ? counts[idx] : 0;
    lds[t] = c;
    __syncthreads();
    for (int off = 1; off < SCAN_B; off <<= 1) {
        int x = lds[t];
        int add = (t >= off) ? lds[t - off] : 0;
        __syncthreads();
        lds[t] = x + add;
        __syncthreads();
    }
    if (idx < nseg) {
        const int off = bsum[blockIdx.x] + lds[t] - c;   // exclusive prefix
        offsets[idx] = off;
        cursor[idx]  = off;
    }
}

// C) scatter row indices into CSR order (int4-vectorized inv loads)
__global__ void scatteridx_kernel(const int* __restrict__ inv,
                                  int* __restrict__ cursor,
                                  int* __restrict__ rowidx, int n) {
    const int stride = gridDim.x * blockDim.x;
    const int n4 = n >> 2;
    const int4* inv4 = (const int4*)inv;
    for (int i = blockIdx.x * blockDim.x + threadIdx.x; i < n4; i += stride) {
        int4 s = inv4[i];
        int base = i << 2;
        rowidx[atomicAdd(&cursor[s.x], 1)] = base + 0;
        rowidx[atomicAdd(&cursor[s.y], 1)] = base + 1;
        rowidx[atomicAdd(&cursor[s.z], 1)] = base + 2;
        rowidx[atomicAdd(&cursor[s.w], 1)] = base + 3;
    }
    if (blockIdx.x == 0 && threadIdx.x < (n & 3)) {
        int i = (n4 << 2) + threadIdx.x;
        rowidx[atomicAdd(&cursor[inv[i]], 1)] = i;
    }
}

// D) gather-reduce: 32 lanes per segment, float4 per lane (128 cols), unroll-4
__global__ void seg_reduce_kernel(const float4* __restrict__ feat4,
                                  const int* __restrict__ rowidx,
                                  const int* __restrict__ offsets,
                                  float4* __restrict__ out4,
                                  int nseg,
                                  const int* __restrict__ mode_p) {
    const int mode = mode_p[0];
    const int t = blockIdx.x * blockDim.x + threadIdx.x;
    const int g = t >> 5;          // segment
    const int q = t & 31;          // float4 column slot
    if (g >= nseg) return;

    const int start = offsets[g];
    const int end   = offsets[g + 1];

    float4 acc;
    if (mode == 1) {
        acc = make_float4(-INFINITY, -INFINITY, -INFINITY, -INFINITY);
        int r = start;
        for (; r + 4 <= end; r += 4) {
            const int row0 = rowidx[r + 0];
            const int row1 = rowidx[r + 1];
            const int row2 = rowidx[r + 2];
            const int row3 = rowidx[r + 3];
            const float4 v0 = feat4[(size_t)row0 * 32 + q];
            const float4 v1 = feat4[(size_t)row1 * 32 + q];
            const float4 v2 = feat4[(size_t)row2 * 32 + q];
            const float4 v3 = feat4[(size_t)row3 * 32 + q];
            acc.x = fmaxf(acc.x, fmaxf(fmaxf(v0.x, v1.x), fmaxf(v2.x, v3.x)));
            acc.y = fmaxf(acc.y, fmaxf(fmaxf(v0.y, v1.y), fmaxf(v2.y, v3.y)));
            acc.z = fmaxf(acc.z, fmaxf(fmaxf(v0.z, v1.z), fmaxf(v2.z, v3.z)));
            acc.w = fmaxf(acc.w, fmaxf(fmaxf(v0.w, v1.w), fmaxf(v2.w, v3.w)));
        }
        for (; r < end; r++) {
            const int row = rowidx[r];
            const float4 v = feat4[(size_t)row * 32 + q];
            acc.x = fmaxf(acc.x, v.x); acc.y = fmaxf(acc.y, v.y);
            acc.z = fmaxf(acc.z, v.z); acc.w = fmaxf(acc.w, v.w);
        }
        if (end == start) acc = make_float4(0.f, 0.f, 0.f, 0.f);  // empty -> 0
    } else {
        acc = make_float4(0.f, 0.f, 0.f, 0.f);
        int r = start;
        for (; r + 4 <= end; r += 4) {
            const int row0 = rowidx[r + 0];
            const int row1 = rowidx[r + 1];
            const int row2 = rowidx[r + 2];
            const int row3 = rowidx[r + 3];
            const float4 v0 = feat4[(size_t)row0 * 32 + q];
            const float4 v1 = feat4[(size_t)row1 * 32 + q];
            const float4 v2 = feat4[(size_t)row2 * 32 + q];
            const float4 v3 = feat4[(size_t)row3 * 32 + q];
            acc.x += (v0.x + v1.x) + (v2.x + v3.x);
            acc.y += (v0.y + v1.y) + (v2.y + v3.y);
            acc.z += (v0.z + v1.z) + (v2.z + v3.z);
            acc.w += (v0.w + v1.w) + (v2.w + v3.w);
        }
        for (; r < end; r++) {
            const int row = rowidx[r];
            const float4 v = feat4[(size_t)row * 32 + q];
            acc.x += v.x; acc.y += v.y; acc.z += v.z; acc.w += v.w;
        }
        if (mode == 2) {
            const float c = fmaxf((float)(end - start), 1.0f);
            acc.x /= c; acc.y /= c; acc.z /= c; acc.w /= c;
        }
    }
    out4[(size_t)g * 32 + q] = acc;
}

// ===========================================================================
// Fallback (atomic path) — only used if ws_size is too small for CSR
// ===========================================================================
__device__ __forceinline__ void atomicMaxFloat(float* addr, float val) {
    if (val >= 0.0f) atomicMax((int*)addr, __float_as_int(val));
    else             atomicMin((unsigned int*)addr, (unsigned int)__float_as_uint(val));
}

__global__ void fb_init_kernel(unsigned int* __restrict__ out, int out_n,
                               float* __restrict__ counts, int nseg,
                               const int* __restrict__ mode_p) {
    const int mode = mode_p[0];
    const unsigned int initv = (mode == 1) ? NEG_INF_BITS : 0u;
    const int stride = gridDim.x * blockDim.x;
    int i = blockIdx.x * blockDim.x + threadIdx.x;
    uint4* out4 = (uint4*)out;
    const int n4 = out_n >> 2;
    uint4 v4 = make_uint4(initv, initv, initv, initv);
    for (int j = i; j < n4; j += stride) out4[j] = v4;
    for (int j = i; j < nseg; j += stride) counts[j] = 0.0f;
}

__global__ void fb_scatter_kernel(const float4* __restrict__ feat4,
                                  const int* __restrict__ inv,
                                  float* __restrict__ out,
                                  float* __restrict__ counts,
                                  int nrows, const int* __restrict__ mode_p) {
    const int mode = mode_p[0];
    const int t = blockIdx.x * blockDim.x + threadIdx.x;
    const int row = t >> 5;
    const int q   = t & 31;
    if (row >= nrows) return;
    const int seg = inv[row];
    const float4 v = feat4[(size_t)row * 32 + q];
    float* dst = out + (size_t)seg * 128 + q * 4;
    if (mode == 1) {
        atomicMaxFloat(dst + 0, v.x); atomicMaxFloat(dst + 1, v.y);
        atomicMaxFloat(dst + 2, v.z); atomicMaxFloat(dst + 3, v.w);
        if (q == 0) atomicAdd(&counts[seg], 1.0f);
    } else {
        atomicAdd(dst + 0, v.x); atomicAdd(dst + 1, v.y);
        atomicAdd(dst + 2, v.z); atomicAdd(dst + 3, v.w);
        if (mode == 2 && q == 0) atomicAdd(&counts[seg], 1.0f);
    }
}

__global__ void fb_fixup_kernel(float* __restrict__ out, int out_n,
                                const float* __restrict__ counts,
                                const int* __restrict__ mode_p) {
    const int mode = mode_p[0];
    if (mode == 3) return;
    const int i = blockIdx.x * blockDim.x + threadIdx.x;
    if (i >= out_n) return;
    const int seg = i >> 7;
    const float c = counts[seg];
    if (mode == 1) { if (c == 0.0f) out[i] = 0.0f; }
    else           { out[i] = out[i] / fmaxf(c, 1.0f); }
}

// ===========================================================================
extern "C" void kernel_launch(void* const* d_in, const int* in_sizes, int n_in,
                              void* d_out, int out_size, void* d_ws, size_t ws_size,
                              hipStream_t stream) {
    const float* feat   = (const float*)d_in[0];
    const int*   inv    = (const int*)d_in[1];
    const int*   mode_p = (const int*)d_in[2];
    float* out = (float*)d_out;

    const int nrows = in_sizes[1];         // 1,000,000
    const int nseg  = out_size / 128;      // 65,536
    const int nblk  = (nseg + SCAN_B - 1) / SCAN_B;   // scan blocks (64)

    // ws layout: counts[nseg] | offsets[nseg+1] | cursor[nseg] | rowidx[nrows] | bsum[nblk]
    const size_t need = (size_t)(nseg + (nseg + 1) + nseg + nrows + nblk) * sizeof(int);

    if (ws_size >= need && nblk <= SCAN_B) {
        int* counts  = (int*)d_ws;
        int* offsets = counts + nseg;
        int* cursor  = offsets + (nseg + 1);
        int* rowidx  = cursor + nseg;
        int* bsum    = rowidx + nrows;

        // A0) zero counts
        {
            dim3 block(256), grid((nseg + 255) / 256);
            zero_counts_kernel<<<grid, block, 0, stream>>>(counts, nseg);
        }
        // A) histogram
        {
            dim3 block(256), grid(1024);
            hist_kernel<<<grid, block, 0, stream>>>(inv, counts, nrows);
        }
        // B) 3-pass coalesced scan
        scan_reduce_kernel<<<nblk, SCAN_B, 0, stream>>>(counts, bsum, nseg);
        scan_top_kernel<<<1, SCAN_B, 0, stream>>>(bsum, offsets, nblk, nseg);
        scan_down_kernel<<<nblk, SCAN_B, 0, stream>>>(counts, bsum, offsets, cursor, nseg);
        // C) scatter row indices
        {
            dim3 block(256), grid(1024);
            scatteridx_kernel<<<grid, block, 0, stream>>>(inv, cursor, rowidx, nrows);
        }
        // D) gather-reduce
        {
            const long long total = (long long)nseg * 32;
            dim3 block(256), grid((unsigned int)((total + 255) / 256));
            seg_reduce_kernel<<<grid, block, 0, stream>>>((const float4*)feat, rowidx,
                                                          offsets, (float4*)out,
                                                          nseg, mode_p);
        }
    } else {
        // fallback: atomic path
        float* counts = (float*)d_ws;
        {
            dim3 block(256), grid(2048);
            fb_init_kernel<<<grid, block, 0, stream>>>((unsigned int*)out, out_size,
                                                       counts, nseg, mode_p);
        }
        {
            const long long total = (long long)nrows * 32;
            dim3 block(256), grid((unsigned int)((total + 255) / 256));
            fb_scatter_kernel<<<grid, block, 0, stream>>>((const float4*)feat, inv,
                                                          out, counts, nrows, mode_p);
        }
        {
            dim3 block(256), grid((out_size + 255) / 256);
            fb_fixup_kernel<<<grid, block, 0, stream>>>(out, out_size, counts, mode_p);
        }
    }
}

// Round 5
// 172.747 us; speedup vs baseline: 15.0478x; 1.3380x over previous
//
#include <hip/hip_runtime.h>
#include <math.h>

#define NEG_INF_BITS 0xFF800000u
#define SCAN_B 1024   // threads per scan block (= tile size)

typedef float f32x4_t __attribute__((ext_vector_type(4)));

__device__ __forceinline__ float4 ld_nt4(const float4* p) {
    f32x4_t v = __builtin_nontemporal_load((const f32x4_t*)p);
    return make_float4(v[0], v[1], v[2], v[3]);
}
__device__ __forceinline__ void st_nt4(float4* p, float4 v) {
    f32x4_t x = {v.x, v.y, v.z, v.w};
    __builtin_nontemporal_store(x, (f32x4_t*)p);
}

// ===========================================================================
// CSR path: zero -> hist+rank -> 3-pass scan -> scatter (no atomics) -> reduce
// ===========================================================================

__global__ void zero_counts_kernel(int* __restrict__ counts, int nseg) {
    const int i = blockIdx.x * blockDim.x + threadIdx.x;
    if (i < nseg) counts[i] = 0;
}

// A) histogram + per-row rank within segment (coalesced rank write)
__global__ void hist_rank_kernel(const int* __restrict__ inv,
                                 int* __restrict__ counts,
                                 int* __restrict__ rank, int n) {
    const int stride = gridDim.x * blockDim.x;
    const int n4 = n >> 2;
    const int4* inv4 = (const int4*)inv;
    int4* rank4 = (int4*)rank;
    for (int i = blockIdx.x * blockDim.x + threadIdx.x; i < n4; i += stride) {
        int4 s = inv4[i];
        int4 rk;
        rk.x = atomicAdd(&counts[s.x], 1);
        rk.y = atomicAdd(&counts[s.y], 1);
        rk.z = atomicAdd(&counts[s.z], 1);
        rk.w = atomicAdd(&counts[s.w], 1);
        rank4[i] = rk;
    }
    if (blockIdx.x == 0 && threadIdx.x < (n & 3)) {
        int i = (n4 << 2) + threadIdx.x;
        rank[i] = atomicAdd(&counts[inv[i]], 1);
    }
}

// B1) per-block reduce of counts tiles -> bsum[block]
__global__ __launch_bounds__(SCAN_B)
void scan_reduce_kernel(const int* __restrict__ counts,
                        int* __restrict__ bsum, int nseg) {
    __shared__ int lds[SCAN_B / 64];
    const int t = threadIdx.x;
    const int idx = blockIdx.x * SCAN_B + t;
    int v = (idx < nseg) ? counts[idx] : 0;
    for (int off = 32; off > 0; off >>= 1) v += __shfl_down(v, off, 64);
    if ((t & 63) == 0) lds[t >> 6] = v;
    __syncthreads();
    if (t < SCAN_B / 64) {
        int s = lds[t];
        for (int off = SCAN_B / 128; off > 0; off >>= 1) s += __shfl_down(s, off, 64);
        if (t == 0) bsum[blockIdx.x] = s;
    }
}

// B2) single small block: exclusive scan of bsum[nblk]; writes offsets[nseg]=total
__global__ __launch_bounds__(SCAN_B)
void scan_top_kernel(int* __restrict__ bsum, int* __restrict__ offsets,
                     int nblk, int nseg) {
    __shared__ int lds[SCAN_B];
    const int t = threadIdx.x;
    int v = (t < nblk) ? bsum[t] : 0;
    lds[t] = v;
    __syncthreads();
    for (int off = 1; off < SCAN_B; off <<= 1) {
        int x = lds[t];
        int add = (t >= off) ? lds[t - off] : 0;
        __syncthreads();
        lds[t] = x + add;
        __syncthreads();
    }
    if (t < nblk) bsum[t] = lds[t] - v;              // exclusive
    if (t == nblk - 1) offsets[nseg] = lds[t];       // total
}

// B3) per-block scan of counts tile + bsum prefix -> offsets
__global__ __launch_bounds__(SCAN_B)
void scan_down_kernel(const int* __restrict__ counts,
                      const int* __restrict__ bsum,
                      int* __restrict__ offsets, int nseg) {
    __shared__ int lds[SCAN_B];
    const int t = threadIdx.x;
    const int idx = blockIdx.x * SCAN_B + t;
    int c = (idx < nseg) ? counts[idx] : 0;
    lds[t] = c;
    __syncthreads();
    for (int off = 1; off < SCAN_B; off <<= 1) {
        int x = lds[t];
        int add = (t >= off) ? lds[t - off] : 0;
        __syncthreads();
        lds[t] = x + add;
        __syncthreads();
    }
    if (idx < nseg) offsets[idx] = bsum[blockIdx.x] + lds[t] - c;  // exclusive
}

// C) scatter row indices into CSR order — NO atomics (uses precomputed rank)
__global__ void scatteridx_kernel(const int* __restrict__ inv,
                                  const int* __restrict__ rank,
                                  const int* __restrict__ offsets,
                                  int* __restrict__ rowidx, int n) {
    const int stride = gridDim.x * blockDim.x;
    const int n4 = n >> 2;
    const int4* inv4 = (const int4*)inv;
    const int4* rank4 = (const int4*)rank;
    for (int i = blockIdx.x * blockDim.x + threadIdx.x; i < n4; i += stride) {
        int4 s  = inv4[i];
        int4 rk = rank4[i];
        int base = i << 2;
        rowidx[offsets[s.x] + rk.x] = base + 0;
        rowidx[offsets[s.y] + rk.y] = base + 1;
        rowidx[offsets[s.z] + rk.z] = base + 2;
        rowidx[offsets[s.w] + rk.w] = base + 3;
    }
    if (blockIdx.x == 0 && threadIdx.x < (n & 3)) {
        int i = (n4 << 2) + threadIdx.x;
        rowidx[offsets[inv[i]] + rank[i]] = i;
    }
}

// D) gather-reduce: 32 lanes per segment, float4 per lane, unroll-8 + nt loads
__global__ void seg_reduce_kernel(const float4* __restrict__ feat4,
                                  const int* __restrict__ rowidx,
                                  const int* __restrict__ offsets,
                                  float4* __restrict__ out4,
                                  int nseg,
                                  const int* __restrict__ mode_p) {
    const int mode = mode_p[0];
    const int t = blockIdx.x * blockDim.x + threadIdx.x;
    const int g = t >> 5;          // segment
    const int q = t & 31;          // float4 column slot
    if (g >= nseg) return;

    const int start = offsets[g];
    const int end   = offsets[g + 1];

    float4 acc;
    if (mode == 1) {
        acc = make_float4(-INFINITY, -INFINITY, -INFINITY, -INFINITY);
        int r = start;
        for (; r + 8 <= end; r += 8) {
            int rows[8];
            #pragma unroll
            for (int k = 0; k < 8; ++k) rows[k] = rowidx[r + k];
            float4 v[8];
            #pragma unroll
            for (int k = 0; k < 8; ++k) v[k] = ld_nt4(feat4 + (size_t)rows[k] * 32 + q);
            #pragma unroll
            for (int k = 0; k < 8; ++k) {
                acc.x = fmaxf(acc.x, v[k].x);
                acc.y = fmaxf(acc.y, v[k].y);
                acc.z = fmaxf(acc.z, v[k].z);
                acc.w = fmaxf(acc.w, v[k].w);
            }
        }
        for (; r + 4 <= end; r += 4) {
            int rows[4];
            #pragma unroll
            for (int k = 0; k < 4; ++k) rows[k] = rowidx[r + k];
            float4 v[4];
            #pragma unroll
            for (int k = 0; k < 4; ++k) v[k] = ld_nt4(feat4 + (size_t)rows[k] * 32 + q);
            #pragma unroll
            for (int k = 0; k < 4; ++k) {
                acc.x = fmaxf(acc.x, v[k].x);
                acc.y = fmaxf(acc.y, v[k].y);
                acc.z = fmaxf(acc.z, v[k].z);
                acc.w = fmaxf(acc.w, v[k].w);
            }
        }
        for (; r < end; r++) {
            const float4 v = ld_nt4(feat4 + (size_t)rowidx[r] * 32 + q);
            acc.x = fmaxf(acc.x, v.x); acc.y = fmaxf(acc.y, v.y);
            acc.z = fmaxf(acc.z, v.z); acc.w = fmaxf(acc.w, v.w);
        }
        if (end == start) acc = make_float4(0.f, 0.f, 0.f, 0.f);  // empty -> 0
    } else {
        acc = make_float4(0.f, 0.f, 0.f, 0.f);
        int r = start;
        for (; r + 8 <= end; r += 8) {
            int rows[8];
            #pragma unroll
            for (int k = 0; k < 8; ++k) rows[k] = rowidx[r + k];
            float4 v[8];
            #pragma unroll
            for (int k = 0; k < 8; ++k) v[k] = ld_nt4(feat4 + (size_t)rows[k] * 32 + q);
            #pragma unroll
            for (int k = 0; k < 8; ++k) {
                acc.x += v[k].x; acc.y += v[k].y; acc.z += v[k].z; acc.w += v[k].w;
            }
        }
        for (; r + 4 <= end; r += 4) {
            int rows[4];
            #pragma unroll
            for (int k = 0; k < 4; ++k) rows[k] = rowidx[r + k];
            float4 v[4];
            #pragma unroll
            for (int k = 0; k < 4; ++k) v[k] = ld_nt4(feat4 + (size_t)rows[k] * 32 + q);
            #pragma unroll
            for (int k = 0; k < 4; ++k) {
                acc.x += v[k].x; acc.y += v[k].y; acc.z += v[k].z; acc.w += v[k].w;
            }
        }
        for (; r < end; r++) {
            const float4 v = ld_nt4(feat4 + (size_t)rowidx[r] * 32 + q);
            acc.x += v.x; acc.y += v.y; acc.z += v.z; acc.w += v.w;
        }
        if (mode == 2) {
            const float c = fmaxf((float)(end - start), 1.0f);
            acc.x /= c; acc.y /= c; acc.z /= c; acc.w /= c;
        }
    }
    st_nt4(out4 + (size_t)g * 32 + q, acc);
}

// ===========================================================================
// Fallback (atomic path) — only used if ws_size is too small for CSR
// ===========================================================================
__device__ __forceinline__ void atomicMaxFloat(float* addr, float val) {
    if (val >= 0.0f) atomicMax((int*)addr, __float_as_int(val));
    else             atomicMin((unsigned int*)addr, (unsigned int)__float_as_uint(val));
}

__global__ void fb_init_kernel(unsigned int* __restrict__ out, int out_n,
                               float* __restrict__ counts, int nseg,
                               const int* __restrict__ mode_p) {
    const int mode = mode_p[0];
    const unsigned int initv = (mode == 1) ? NEG_INF_BITS : 0u;
    const int stride = gridDim.x * blockDim.x;
    int i = blockIdx.x * blockDim.x + threadIdx.x;
    uint4* out4 = (uint4*)out;
    const int n4 = out_n >> 2;
    uint4 v4 = make_uint4(initv, initv, initv, initv);
    for (int j = i; j < n4; j += stride) out4[j] = v4;
    for (int j = i; j < nseg; j += stride) counts[j] = 0.0f;
}

__global__ void fb_scatter_kernel(const float4* __restrict__ feat4,
                                  const int* __restrict__ inv,
                                  float* __restrict__ out,
                                  float* __restrict__ counts,
                                  int nrows, const int* __restrict__ mode_p) {
    const int mode = mode_p[0];
    const int t = blockIdx.x * blockDim.x + threadIdx.x;
    const int row = t >> 5;
    const int q   = t & 31;
    if (row >= nrows) return;
    const int seg = inv[row];
    const float4 v = ((const float4*)feat4)[(size_t)row * 32 + q];
    float* dst = out + (size_t)seg * 128 + q * 4;
    if (mode == 1) {
        atomicMaxFloat(dst + 0, v.x); atomicMaxFloat(dst + 1, v.y);
        atomicMaxFloat(dst + 2, v.z); atomicMaxFloat(dst + 3, v.w);
        if (q == 0) atomicAdd(&counts[seg], 1.0f);
    } else {
        atomicAdd(dst + 0, v.x); atomicAdd(dst + 1, v.y);
        atomicAdd(dst + 2, v.z); atomicAdd(dst + 3, v.w);
        if (mode == 2 && q == 0) atomicAdd(&counts[seg], 1.0f);
    }
}

__global__ void fb_fixup_kernel(float* __restrict__ out, int out_n,
                                const float* __restrict__ counts,
                                const int* __restrict__ mode_p) {
    const int mode = mode_p[0];
    if (mode == 3) return;
    const int i = blockIdx.x * blockDim.x + threadIdx.x;
    if (i >= out_n) return;
    const int seg = i >> 7;
    const float c = counts[seg];
    if (mode == 1) { if (c == 0.0f) out[i] = 0.0f; }
    else           { out[i] = out[i] / fmaxf(c, 1.0f); }
}

// ===========================================================================
extern "C" void kernel_launch(void* const* d_in, const int* in_sizes, int n_in,
                              void* d_out, int out_size, void* d_ws, size_t ws_size,
                              hipStream_t stream) {
    const float* feat   = (const float*)d_in[0];
    const int*   inv    = (const int*)d_in[1];
    const int*   mode_p = (const int*)d_in[2];
    float* out = (float*)d_out;

    const int nrows = in_sizes[1];         // 1,000,000
    const int nseg  = out_size / 128;      // 65,536
    const int nblk  = (nseg + SCAN_B - 1) / SCAN_B;   // scan blocks (64)

    // ws layout: counts[nseg] | offsets[nseg+1] | rowidx[nrows] | bsum[nblk] | rank[nrows]
    const size_t need = (size_t)(nseg + (nseg + 1) + nrows + nblk + nrows) * sizeof(int);

    if (ws_size >= need && nblk <= SCAN_B) {
        int* counts  = (int*)d_ws;
        int* offsets = counts + nseg;
        int* rowidx  = offsets + (nseg + 1);
        int* bsum    = rowidx + nrows;
        int* rank    = bsum + nblk;

        // A0) zero counts
        {
            dim3 block(256), grid((nseg + 255) / 256);
            zero_counts_kernel<<<grid, block, 0, stream>>>(counts, nseg);
        }
        // A) histogram + rank
        {
            dim3 block(256), grid(1024);
            hist_rank_kernel<<<grid, block, 0, stream>>>(inv, counts, rank, nrows);
        }
        // B) 3-pass coalesced scan
        scan_reduce_kernel<<<nblk, SCAN_B, 0, stream>>>(counts, bsum, nseg);
        scan_top_kernel<<<1, SCAN_B, 0, stream>>>(bsum, offsets, nblk, nseg);
        scan_down_kernel<<<nblk, SCAN_B, 0, stream>>>(counts, bsum, offsets, nseg);
        // C) scatter row indices (atomic-free)
        {
            dim3 block(256), grid(1024);
            scatteridx_kernel<<<grid, block, 0, stream>>>(inv, rank, offsets, rowidx, nrows);
        }
        // D) gather-reduce
        {
            const long long total = (long long)nseg * 32;
            dim3 block(256), grid((unsigned int)((total + 255) / 256));
            seg_reduce_kernel<<<grid, block, 0, stream>>>((const float4*)feat, rowidx,
                                                          offsets, (float4*)out,
                                                          nseg, mode_p);
        }
    } else {
        // fallback: atomic path
        float* counts = (float*)d_ws;
        {
            dim3 block(256), grid(2048);
            fb_init_kernel<<<grid, block, 0, stream>>>((unsigned int*)out, out_size,
                                                       counts, nseg, mode_p);
        }
        {
            const long long total = (long long)nrows * 32;
            dim3 block(256), grid((unsigned int)((total + 255) / 256));
            fb_scatter_kernel<<<grid, block, 0, stream>>>((const float4*)feat, inv,
                                                          out, counts, nrows, mode_p);
        }
        {
            dim3 block(256), grid((out_size + 255) / 256);
            fb_fixup_kernel<<<grid, block, 0, stream>>>(out, out_size, counts, mode_p);
        }
    }
}